// Round 9
// baseline (32.254 us; speedup 1.0000x reference)
//
#include <hip/hip_runtime.h>
#include <math.h>

// ---------------------------------------------------------------------------
// SpikingColorVision: 4 pops x 8 ch Izhikevich RS neurons, 1000 Euler steps.
// Single 64-lane wave. REGIME (R6/R7 A/B): ISSUE-bound at ~2.69ns per wave64
// instruction (2cy @ ~745MHz lone-wave clock; DVFS does not ramp inside graph
// replays -- R3/R5 burners failed). Chain has slack (20cy issue > 16-20cy
// chain), so ONLY instruction count matters.
//
// R9: pack the two independent constant-coefficient h1 FMAs into ONE
// v_pk_fma_f32 (gfx90a+ dual FP32):
//   (d3, w) = pk_fma( (-.004, .04), (U, v), (I3, 6) )
// State kept as float2 pair X = (U, v); c-pair has .y=6 invariant and
// .x = I3 = fma(.3, eps, Ib140) written per step into the pair's low reg.
// Bit-identical math (pk = two IEEE fmas). 10 inst/step:
//   load, I3, pk(d3,w), Un, vn, cmp, sv-sel, v-sel, U-fma, R-fma
// ---------------------------------------------------------------------------

typedef float float2v __attribute__((ext_vector_type(2)));

// X.x = U (=250*u), X.y = v. cf = (-.004, .04). cp.y = 6 (invariant).
#define FSTEP(eps) do {                                  \
    cp.x = __builtin_fmaf(0.3f, (eps), Ib140);           \
    float2v dw_;                                         \
    asm("v_pk_fma_f32 %0, %1, %2, %3"                    \
        : "=v"(dw_) : "v"(cf), "v"(X), "v"(cp));         \
    float Un_ = __builtin_fmaf(0.98f, X.x, X.y);         \
    float vn_ = __builtin_fmaf(dw_.y, X.y, dw_.x);       \
    bool  sp_ = (vn_ >= 30.0f);                          \
    float sv_ = sp_ ? 1.0f : 0.0f;                       \
    X.y = sp_ ? -65.0f : vn_;                            \
    X.x = __builtin_fmaf(2000.0f, sv_, Un_);             \
    R = __builtin_fmaf(0.95f, R, sv_);                   \
  } while (0)

// 16 loads, stride 32 floats (128B) -> immediate offsets, one base register.
#define LOAD16(B, base) do {                             \
    B##0  = (base)[0*32];  B##1  = (base)[1*32];         \
    B##2  = (base)[2*32];  B##3  = (base)[3*32];         \
    B##4  = (base)[4*32];  B##5  = (base)[5*32];         \
    B##6  = (base)[6*32];  B##7  = (base)[7*32];         \
    B##8  = (base)[8*32];  B##9  = (base)[9*32];         \
    B##10 = (base)[10*32]; B##11 = (base)[11*32];        \
    B##12 = (base)[12*32]; B##13 = (base)[13*32];        \
    B##14 = (base)[14*32]; B##15 = (base)[15*32];        \
  } while (0)

#define STEP16(B) do {                                   \
    FSTEP(B##0);  FSTEP(B##1);  FSTEP(B##2);  FSTEP(B##3);   \
    FSTEP(B##4);  FSTEP(B##5);  FSTEP(B##6);  FSTEP(B##7);   \
    FSTEP(B##8);  FSTEP(B##9);  FSTEP(B##10); FSTEP(B##11);  \
    FSTEP(B##12); FSTEP(B##13); FSTEP(B##14); FSTEP(B##15);  \
  } while (0)

#define CLS(tv) do {                                     \
    f  += ((tv) > 0.7f) ? 1.0f : 0.0f;                   \
    e  += (fabsf((tv) - 0.5f)  < 0.1f) ? 1.0f : 0.0f;    \
    r  += (fabsf((tv) - 0.75f) < 0.1f) ? 1.0f : 0.0f;    \
    cp += (fabsf((tv) - 0.25f) < 0.1f) ? 1.0f : 0.0f;    \
  } while (0)

// Single kernel: drives + 1000-step recurrence + outputs, one 64-lane wave.
__global__ __launch_bounds__(64) void scv_kernel(
    const float* __restrict__ retL, const float* __restrict__ retR,
    const float* __restrict__ noise, float* __restrict__ out, int S) {
  const int lane = threadIdx.x;
  const int neuron = lane & 31;  // upper 32 lanes duplicate (wave64 uniform)

  // ---- issue the first noise block's loads NOW (latency hides under the
  //      drives computation below) ----
  const float* p = noise + neuron;
  float c0,c1,c2,c3,c4,c5,c6,c7,c8,c9,c10,c11,c12,c13,c14,c15;
  float n0,n1,n2,n3,n4,n5,n6,n7,n8,n9,n10,n11,n12,n13,n14,n15;
  const bool main_path = (S >= 48);
  if (main_path) { LOAD16(c, p); p += 16 * 32; }

  // ---- drives (exact integer counts; any reduction order exact) ----
  float Ib140;
  {
#pragma clang fp contract(off)
    const float4* L4 = reinterpret_cast<const float4*>(retL);
    const float4* R4 = reinterpret_cast<const float4*>(retR);
    float f = 0.0f, e = 0.0f, r = 0.0f, cp = 0.0f;
#pragma unroll
    for (int it = 0; it < 4; ++it) {
      int g = lane + (it << 6);           // 0..255 over 200 float4s
      if (g < 200) {
        float4 q = (g < 100) ? L4[g] : R4[g - 100];
        CLS(q.x); CLS(q.y); CLS(q.z); CLS(q.w);
      }
    }
#pragma unroll
    for (int off = 1; off < 64; off <<= 1) {
      f  += __shfl_xor(f,  off);
      e  += __shfl_xor(e,  off);
      r  += __shfl_xor(r,  off);
      cp += __shfl_xor(cp, off);
    }
    float total = f + e + r + cp + 1e-8f;
    int pp = (lane >> 3) & 3;
    float dv;
    if (pp == 0)      dv = (f * 0.1f + e * 0.05f + cp * 0.8f + r * 0.2f) / total;
    else if (pp == 1) dv = (f * 0.2f + e * 0.1f  + cp * 0.5f + r * 0.3f) / total;
    else if (pp == 2) dv = (f * 0.8f + e * 0.3f  + cp * 0.3f + r * 0.3f) / total;
    else              dv = (f * 0.4f + e * 0.7f  + cp * 0.2f + r * 0.3f) / total;
    float Ib = dv * 10.0f + (-2.0f);
    Ib140 = Ib + 140.0f;
  }

  // ---- recurrence ----
  float2v X;                 // X.x = U = 250*u, X.y = v
  X.x = -3250.0f;            // 250 * u0, u0 = -13 exactly
  X.y = -65.0f;
  float R = 0.0f;            // rate / 0.05
  float2v cf; cf.x = -0.004f; cf.y = 0.04f;   // pk coefficients (invariant)
  float2v cp; cp.x = 0.0f;   cp.y = 6.0f;     // .x = I3 per step, .y invariant

  int t = 0;
  if (main_path) {
    for (; t + 48 <= S; t += 32) {
      LOAD16(n, p); p += 16 * 32;          // steps t+16..t+31
      STEP16(c);                           // steps t..t+15
      LOAD16(c, p); p += 16 * 32;          // steps t+32..t+47
      STEP16(n);                           // steps t+16..t+31
    }
    STEP16(c);                             // steps t..t+15
    t += 16;
  }
  // tail: 1-ahead prefetch scalar loop
  {
    const float* q = noise + neuron;
    float cur = (t < S) ? q[(size_t)t * 32] : 0.0f;
    for (; t < S; ++t) {
      float nxt = (t + 1 < S) ? q[(size_t)(t + 1) * 32] : 0.0f;
      FSTEP(cur);
      cur = nxt;
    }
  }

  // ---- outputs ----
  {
#pragma clang fp contract(off)
    float rate = 0.05f * R;
    float rsum = rate;
    rsum += __shfl_xor(rsum, 1);
    rsum += __shfl_xor(rsum, 2);
    rsum += __shfl_xor(rsum, 4);
    float mean = rsum / 8.0f;            // exact /8
    float m_uv = __shfl(mean, 0);
    float m_bl = __shfl(mean, 8);
    float m_gr = __shfl(mean, 16);
    float m_rd = __shfl(mean, 24);
    if (lane == 0) {
      out[0] = m_uv;
      out[1] = m_bl;
      out[2] = m_gr;
      out[3] = m_rd;
      out[4] = m_rd - m_gr;
      out[5] = (m_uv + m_bl) / 2.0f - (m_gr + m_rd) / 2.0f;
    }
  }
}

extern "C" void kernel_launch(void* const* d_in, const int* in_sizes, int n_in,
                              void* d_out, int out_size, void* d_ws,
                              size_t ws_size, hipStream_t stream) {
  const float* retL  = (const float*)d_in[0];
  const float* retR  = (const float*)d_in[1];
  const float* noise = (const float*)d_in[2];
  float* out = (float*)d_out;
  (void)n_in; (void)out_size; (void)d_ws; (void)ws_size;

  const int S = in_sizes[2] / 32;  // substeps
  hipLaunchKernelGGL(scv_kernel, dim3(1), dim3(64), 0, stream, retL, retR,
                     noise, out, S);
}

// Round 10
// 32.024 us; speedup vs baseline: 1.0072x; 1.0072x over previous
//
#include <hip/hip_runtime.h>
#include <math.h>

// ---------------------------------------------------------------------------
// SpikingColorVision: 4 pops x 8 ch Izhikevich RS neurons, 1000 Euler steps.
// Single 64-lane wave. REGIME (R6/R7/R9 A/Bs): ISSUE-bound at ~2.7ns per
// wave64 instruction (2cy @ ~745MHz lone-wave clock; DVFS does not ramp
// inside graph replays -- R3/R5 burners failed; chain length has slack --
// R7 4-hop == R6 5-hop; pk_fma packing is canceled by the pair-insert mov --
// R9). The 11-instruction step is the issue floor:
//   load, I3=fma(.3,eps,Ib140), d3=fma(-.004,U,I3), w=fma(.04,v,6),
//   Un=fma(.98,U,v), vn=fma(w,v,d3), cmp, sv-sel, v-sel,
//   U'=fma(2000,sv,Un), R'=fma(.95,R,sv)
// Total = 29.6us sim + ~1us drives/tail/output + ~1.3us launch overhead.
// This file is the R8 configuration (measured 31.94us), restored.
// ---------------------------------------------------------------------------

#define FSTEP(eps) do {                                  \
    float I3_ = __builtin_fmaf(0.3f, (eps), Ib140);      \
    float d3_ = __builtin_fmaf(-0.004f, U, I3_);         \
    float w_  = __builtin_fmaf(0.04f, v, 6.0f);          \
    float Un_ = __builtin_fmaf(0.98f, U, v);             \
    float vn_ = __builtin_fmaf(w_, v, d3_);              \
    bool  sp_ = (vn_ >= 30.0f);                          \
    float sv_ = sp_ ? 1.0f : 0.0f;                       \
    v = sp_ ? -65.0f : vn_;                              \
    U = __builtin_fmaf(2000.0f, sv_, Un_);               \
    R = __builtin_fmaf(0.95f, R, sv_);                   \
  } while (0)

// 16 loads, stride 32 floats (128B) -> immediate offsets, one base register.
#define LOAD16(B, base) do {                             \
    B##0  = (base)[0*32];  B##1  = (base)[1*32];         \
    B##2  = (base)[2*32];  B##3  = (base)[3*32];         \
    B##4  = (base)[4*32];  B##5  = (base)[5*32];         \
    B##6  = (base)[6*32];  B##7  = (base)[7*32];         \
    B##8  = (base)[8*32];  B##9  = (base)[9*32];         \
    B##10 = (base)[10*32]; B##11 = (base)[11*32];        \
    B##12 = (base)[12*32]; B##13 = (base)[13*32];        \
    B##14 = (base)[14*32]; B##15 = (base)[15*32];        \
  } while (0)

#define STEP16(B) do {                                   \
    FSTEP(B##0);  FSTEP(B##1);  FSTEP(B##2);  FSTEP(B##3);   \
    FSTEP(B##4);  FSTEP(B##5);  FSTEP(B##6);  FSTEP(B##7);   \
    FSTEP(B##8);  FSTEP(B##9);  FSTEP(B##10); FSTEP(B##11);  \
    FSTEP(B##12); FSTEP(B##13); FSTEP(B##14); FSTEP(B##15);  \
  } while (0)

#define CLS(tv) do {                                     \
    f  += ((tv) > 0.7f) ? 1.0f : 0.0f;                   \
    e  += (fabsf((tv) - 0.5f)  < 0.1f) ? 1.0f : 0.0f;    \
    r  += (fabsf((tv) - 0.75f) < 0.1f) ? 1.0f : 0.0f;    \
    cp += (fabsf((tv) - 0.25f) < 0.1f) ? 1.0f : 0.0f;    \
  } while (0)

// Single kernel: drives + 1000-step recurrence + outputs, one 64-lane wave.
__global__ __launch_bounds__(64) void scv_kernel(
    const float* __restrict__ retL, const float* __restrict__ retR,
    const float* __restrict__ noise, float* __restrict__ out, int S) {
  const int lane = threadIdx.x;
  const int neuron = lane & 31;  // upper 32 lanes duplicate (wave64 uniform)

  // ---- issue the first noise block's loads NOW (latency hides under the
  //      drives computation below) ----
  const float* p = noise + neuron;
  float c0,c1,c2,c3,c4,c5,c6,c7,c8,c9,c10,c11,c12,c13,c14,c15;
  float n0,n1,n2,n3,n4,n5,n6,n7,n8,n9,n10,n11,n12,n13,n14,n15;
  const bool main_path = (S >= 48);
  if (main_path) { LOAD16(c, p); p += 16 * 32; }

  // ---- drives (exact integer counts; any reduction order exact) ----
  float Ib140;
  {
#pragma clang fp contract(off)
    const float4* L4 = reinterpret_cast<const float4*>(retL);
    const float4* R4 = reinterpret_cast<const float4*>(retR);
    float f = 0.0f, e = 0.0f, r = 0.0f, cp = 0.0f;
#pragma unroll
    for (int it = 0; it < 4; ++it) {
      int g = lane + (it << 6);           // 0..255 over 200 float4s
      if (g < 200) {
        float4 q = (g < 100) ? L4[g] : R4[g - 100];
        CLS(q.x); CLS(q.y); CLS(q.z); CLS(q.w);
      }
    }
#pragma unroll
    for (int off = 1; off < 64; off <<= 1) {
      f  += __shfl_xor(f,  off);
      e  += __shfl_xor(e,  off);
      r  += __shfl_xor(r,  off);
      cp += __shfl_xor(cp, off);
    }
    float total = f + e + r + cp + 1e-8f;
    int pp = (lane >> 3) & 3;
    float dv;
    if (pp == 0)      dv = (f * 0.1f + e * 0.05f + cp * 0.8f + r * 0.2f) / total;
    else if (pp == 1) dv = (f * 0.2f + e * 0.1f  + cp * 0.5f + r * 0.3f) / total;
    else if (pp == 2) dv = (f * 0.8f + e * 0.3f  + cp * 0.3f + r * 0.3f) / total;
    else              dv = (f * 0.4f + e * 0.7f  + cp * 0.2f + r * 0.3f) / total;
    float Ib = dv * 10.0f + (-2.0f);
    Ib140 = Ib + 140.0f;
  }

  // ---- recurrence ----
  float v = -65.0f;
  float U = -3250.0f;   // 250 * u0, u0 = -13 exactly
  float R = 0.0f;       // rate / 0.05

  int t = 0;
  if (main_path) {
    for (; t + 48 <= S; t += 32) {
      LOAD16(n, p); p += 16 * 32;          // steps t+16..t+31
      STEP16(c);                           // steps t..t+15
      LOAD16(c, p); p += 16 * 32;          // steps t+32..t+47
      STEP16(n);                           // steps t+16..t+31
    }
    STEP16(c);                             // steps t..t+15
    t += 16;
  }
  // tail: 1-ahead prefetch scalar loop
  {
    const float* q = noise + neuron;
    float cur = (t < S) ? q[(size_t)t * 32] : 0.0f;
    for (; t < S; ++t) {
      float nxt = (t + 1 < S) ? q[(size_t)(t + 1) * 32] : 0.0f;
      FSTEP(cur);
      cur = nxt;
    }
  }

  // ---- outputs ----
  {
#pragma clang fp contract(off)
    float rate = 0.05f * R;
    float rsum = rate;
    rsum += __shfl_xor(rsum, 1);
    rsum += __shfl_xor(rsum, 2);
    rsum += __shfl_xor(rsum, 4);
    float mean = rsum / 8.0f;            // exact /8
    float m_uv = __shfl(mean, 0);
    float m_bl = __shfl(mean, 8);
    float m_gr = __shfl(mean, 16);
    float m_rd = __shfl(mean, 24);
    if (lane == 0) {
      out[0] = m_uv;
      out[1] = m_bl;
      out[2] = m_gr;
      out[3] = m_rd;
      out[4] = m_rd - m_gr;
      out[5] = (m_uv + m_bl) / 2.0f - (m_gr + m_rd) / 2.0f;
    }
  }
}

extern "C" void kernel_launch(void* const* d_in, const int* in_sizes, int n_in,
                              void* d_out, int out_size, void* d_ws,
                              size_t ws_size, hipStream_t stream) {
  const float* retL  = (const float*)d_in[0];
  const float* retR  = (const float*)d_in[1];
  const float* noise = (const float*)d_in[2];
  float* out = (float*)d_out;
  (void)n_in; (void)out_size; (void)d_ws; (void)ws_size;

  const int S = in_sizes[2] / 32;  // substeps
  hipLaunchKernelGGL(scv_kernel, dim3(1), dim3(64), 0, stream, retL, retR,
                     noise, out, S);
}